// Round 1
// baseline (2163.520 us; speedup 1.0000x reference)
//
#include <hip/hip_runtime.h>

// ---------------------------------------------------------------------------
// GCN 2-layer: GCNConv(128->32) -> BN -> ReLU -> GCNConv(32->16)
// N=100000, E=3200000. All fp32.
// ---------------------------------------------------------------------------

__global__ __launch_bounds__(256) void k_deg(const int* __restrict__ dst,
                                             const float* __restrict__ w,
                                             float* __restrict__ deg, int E) {
    int i = blockIdx.x * 256 + threadIdx.x;
    if (i < E) atomicAdd(&deg[dst[i]], w[i]);
}

__global__ __launch_bounds__(256) void k_dinv(const float* __restrict__ deg,
                                              float* __restrict__ dinv, int N) {
    int i = blockIdx.x * 256 + threadIdx.x;
    if (i < N) dinv[i] = rsqrtf(deg[i] + 1.0f);  // +1 = self-loop weight
}

// h1 = x @ W1  [N,128]x[128,32]; also agg1 = dinv^2 * h1 (self-loop term).
// Block: 256 threads, 256 rows. Thread tile: 4 rows x 8 cols.
__global__ __launch_bounds__(256) void k_gemm1(const float* __restrict__ x,
                                               const float* __restrict__ W1,
                                               const float* __restrict__ dinv,
                                               float* __restrict__ h1,
                                               float* __restrict__ agg1, int N) {
    __shared__ float Wl[128 * 32];   // 16 KB
    __shared__ float Xl[256 * 33];   // 33.8 KB, pad 33 -> 2-way bank alias (free)
    const int tid = threadIdx.x;
    const long rowbase = (long)blockIdx.x * 256;

    for (int i = tid; i < 128 * 32; i += 256) Wl[i] = W1[i];

    const int rg = tid >> 2;   // 0..63 row group (4 rows each)
    const int cg = tid & 3;    // 0..3  col group (8 cols each)

    float acc[4][8];
#pragma unroll
    for (int i = 0; i < 4; i++)
#pragma unroll
        for (int j = 0; j < 8; j++) acc[i][j] = 0.0f;

    for (int c = 0; c < 4; c++) {   // K chunks of 32
        __syncthreads();
        // stage X[:, c*32 .. c*32+31]
#pragma unroll
        for (int p = 0; p < 8; p++) {
            int r = p * 32 + (tid >> 3);
            int q = tid & 7;
            long row = rowbase + r;
            float4 v = make_float4(0.f, 0.f, 0.f, 0.f);
            if (row < N) v = *(const float4*)(x + row * 128 + c * 32 + q * 4);
            float* xp = &Xl[r * 33 + q * 4];
            xp[0] = v.x; xp[1] = v.y; xp[2] = v.z; xp[3] = v.w;
        }
        __syncthreads();
#pragma unroll
        for (int k = 0; k < 32; k++) {
            float xv[4];
#pragma unroll
            for (int i = 0; i < 4; i++) xv[i] = Xl[(rg * 4 + i) * 33 + k];
            const float* wrow = &Wl[(c * 32 + k) * 32 + cg * 8];
#pragma unroll
            for (int j = 0; j < 8; j++) {
                float wv = wrow[j];
#pragma unroll
                for (int i = 0; i < 4; i++) acc[i][j] = fmaf(xv[i], wv, acc[i][j]);
            }
        }
    }
#pragma unroll
    for (int i = 0; i < 4; i++) {
        long row = rowbase + rg * 4 + i;
        if (row < N) {
            float di = dinv[row];
            float dd = di * di;
            float* hp = h1 + row * 32 + cg * 8;
            float* ap = agg1 + row * 32 + cg * 8;
#pragma unroll
            for (int j = 0; j < 8; j++) { hp[j] = acc[i][j]; ap[j] = dd * acc[i][j]; }
        }
    }
}

// agg1[dst] += norm * h1[src]; 8 threads per edge (32 feats / float4 quads)
__global__ __launch_bounds__(256) void k_scatter1(const int* __restrict__ src,
                                                  const int* __restrict__ dst,
                                                  const float* __restrict__ w,
                                                  const float* __restrict__ dinv,
                                                  const float* __restrict__ h1,
                                                  float* __restrict__ agg1, int E) {
    long gid = (long)blockIdx.x * 256 + threadIdx.x;
    long e = gid >> 3;
    int q = (int)(gid & 7);
    if (e < E) {
        int s = src[e], d = dst[e];
        float nw = dinv[s] * w[e] * dinv[d];
        float4 v = *(const float4*)(h1 + (long)s * 32 + q * 4);
        float* op = agg1 + (long)d * 32 + q * 4;
        atomicAdd(op + 0, nw * v.x);
        atomicAdd(op + 1, nw * v.y);
        atomicAdd(op + 2, nw * v.z);
        atomicAdd(op + 3, nw * v.w);
    }
}

// per-feature sum and sum-of-squares over agg1 [N,32]
__global__ __launch_bounds__(256) void k_stats(const float* __restrict__ agg1,
                                               float* __restrict__ stats, long total) {
    __shared__ float sd[256], sq[256];
    int tid = threadIdx.x;
    float s = 0.f, ss = 0.f;
    for (long i = (long)blockIdx.x * 256 + tid; i < total; i += (long)gridDim.x * 256) {
        float v = agg1[i];
        s += v; ss += v * v;
    }
    sd[tid] = s; sq[tid] = ss;
    __syncthreads();
    for (int off = 128; off >= 32; off >>= 1) {   // offsets are multiples of 32:
        if (tid < off) { sd[tid] += sd[tid + off]; sq[tid] += sq[tid + off]; }
        __syncthreads();
    }
    if (tid < 32) {
        atomicAdd(&stats[tid], sd[tid]);
        atomicAdd(&stats[32 + tid], sq[tid]);
    }
}

__global__ void k_finalize(const float* __restrict__ stats,
                           const float* __restrict__ gamma,
                           const float* __restrict__ beta,
                           float* __restrict__ ss, float invN) {
    int f = threadIdx.x;
    if (f < 32) {
        float mean = stats[f] * invN;
        float var = stats[32 + f] * invN - mean * mean;
        float rs = rsqrtf(fmaxf(var, 0.0f) + 1e-5f);
        float sc = gamma[f] * rs;
        ss[f] = sc;                      // scale
        ss[32 + f] = beta[f] - mean * sc; // shift (b1 cancels in BN)
    }
}

// fused: h = relu(agg1*scale+shift); h2 = h @ W2 [32x16];
// out = b2 + dinv^2 * h2 (self-loop init). 64 nodes per 256-thread block.
__global__ __launch_bounds__(256) void k_l2(const float* __restrict__ agg1,
                                            const float* __restrict__ W2,
                                            const float* __restrict__ ss,
                                            const float* __restrict__ dinv,
                                            const float* __restrict__ b2,
                                            float* __restrict__ h2,
                                            float* __restrict__ out, int N) {
    __shared__ float W2l[512];
    __shared__ float Hl[64 * 33];
    __shared__ float scl[32], shf[32];
    int tid = threadIdx.x;
    for (int i = tid; i < 512; i += 256) W2l[i] = W2[i];
    if (tid < 32) { scl[tid] = ss[tid]; shf[tid] = ss[32 + tid]; }
    __syncthreads();

    long nb = (long)blockIdx.x * 64;
#pragma unroll
    for (int p = 0; p < 2; p++) {
        int idx4 = p * 256 + tid;          // 512 float4 = 64 rows x 32
        long row = nb + (idx4 >> 3);
        int c0 = (idx4 & 7) * 4;
        float4 v = make_float4(0.f, 0.f, 0.f, 0.f);
        if (row < N) v = *(const float4*)(agg1 + row * 32 + c0);
        int lr = idx4 >> 3;
        float* hp = &Hl[lr * 33 + c0];
        hp[0] = fmaxf(0.f, v.x * scl[c0 + 0] + shf[c0 + 0]);
        hp[1] = fmaxf(0.f, v.y * scl[c0 + 1] + shf[c0 + 1]);
        hp[2] = fmaxf(0.f, v.z * scl[c0 + 2] + shf[c0 + 2]);
        hp[3] = fmaxf(0.f, v.w * scl[c0 + 3] + shf[c0 + 3]);
    }
    __syncthreads();
#pragma unroll
    for (int p = 0; p < 4; p++) {
        int o = p * 256 + tid;             // 1024 outputs = 64 nodes x 16
        int n = o >> 4, f = o & 15;
        float a = 0.f;
#pragma unroll
        for (int k = 0; k < 32; k++) a = fmaf(Hl[n * 33 + k], W2l[k * 16 + f], a);
        long row = nb + n;
        if (row < N) {
            h2[row * 16 + f] = a;
            float di = dinv[row];
            out[row * 16 + f] = b2[f] + di * di * a;
        }
    }
}

// out[dst] += norm * h2[src]; 4 threads per edge (16 feats)
__global__ __launch_bounds__(256) void k_scatter2(const int* __restrict__ src,
                                                  const int* __restrict__ dst,
                                                  const float* __restrict__ w,
                                                  const float* __restrict__ dinv,
                                                  const float* __restrict__ h2,
                                                  float* __restrict__ out, int E) {
    long gid = (long)blockIdx.x * 256 + threadIdx.x;
    long e = gid >> 2;
    int q = (int)(gid & 3);
    if (e < E) {
        int s = src[e], d = dst[e];
        float nw = dinv[s] * w[e] * dinv[d];
        float4 v = *(const float4*)(h2 + (long)s * 16 + q * 4);
        float* op = out + (long)d * 16 + q * 4;
        atomicAdd(op + 0, nw * v.x);
        atomicAdd(op + 1, nw * v.y);
        atomicAdd(op + 2, nw * v.z);
        atomicAdd(op + 3, nw * v.w);
    }
}

extern "C" void kernel_launch(void* const* d_in, const int* in_sizes, int n_in,
                              void* d_out, int out_size, void* d_ws, size_t ws_size,
                              hipStream_t stream) {
    const float* x     = (const float*)d_in[0];
    const int*   ei    = (const int*)d_in[1];
    const float* ea    = (const float*)d_in[2];
    const float* W1    = (const float*)d_in[3];
    // d_in[4] = b1: cancels inside BatchNorm (mean subtraction) -> unused
    const float* gamma = (const float*)d_in[5];
    const float* beta  = (const float*)d_in[6];
    const float* W2    = (const float*)d_in[7];
    const float* b2    = (const float*)d_in[8];

    const int N = in_sizes[0] / 128;
    const int E = in_sizes[2];
    const int* src = ei;
    const int* dst = ei + E;

    const long Npad = (long)((N + 63) & ~63);
    float* ws    = (float*)d_ws;
    float* deg   = ws;                       // [Npad]
    float* stats = ws + Npad;                // [64]
    float* ssb   = ws + Npad + 64;           // [64] scale/shift
    float* dinv  = ws + Npad + 128;          // [Npad]
    float* h1    = dinv + Npad;              // [Npad*32]
    float* agg1  = h1 + 32 * Npad;           // [Npad*32]
    float* h2    = h1;                       // alias: h1 dead after scatter1
    float* out   = (float*)d_out;

    hipMemsetAsync(deg, 0, (size_t)(Npad + 128) * sizeof(float), stream);

    k_deg<<<(E + 255) / 256, 256, 0, stream>>>(dst, ea, deg, E);
    k_dinv<<<(N + 255) / 256, 256, 0, stream>>>(deg, dinv, N);
    k_gemm1<<<(N + 255) / 256, 256, 0, stream>>>(x, W1, dinv, h1, agg1, N);
    k_scatter1<<<(int)(((long)E * 8 + 255) / 256), 256, 0, stream>>>(src, dst, ea, dinv, h1, agg1, E);
    k_stats<<<1024, 256, 0, stream>>>(agg1, stats, (long)N * 32);
    k_finalize<<<1, 64, 0, stream>>>(stats, gamma, beta, ssb, 1.0f / (float)N);
    k_l2<<<(N + 63) / 64, 256, 0, stream>>>(agg1, W2, ssb, dinv, b2, h2, out, N);
    k_scatter2<<<(int)(((long)E * 4 + 255) / 256), 256, 0, stream>>>(src, dst, ea, dinv, h2, out, E);
}